// Round 2
// baseline (280.946 us; speedup 1.0000x reference)
//
#include <hip/hip_runtime.h>
#include <hip/hip_bf16.h>
#include <math.h>

#define NN 50000
#define EE 640000
#define DD 128
#define NREL 8
#define NCLS 16
#define NBUCK (NREL * NN)              // 400000 buckets, key = dst*8 + rel (dst-major)
#define SCAN_NB ((NBUCK + 255) / 256)  // 1563
#define NBIN 64
#define RECCAP 40                      // max cached recs/node in LDS (total deg ~12.8 avg, max ~33)
#define TNODES 32                      // nodes per fused1 block

typedef __attribute__((ext_vector_type(8))) short short8;   // 8 bf16 = 4 VGPRs
typedef __attribute__((ext_vector_type(4))) float f32x4;    // MFMA acc

__device__ __forceinline__ float bflo(unsigned u) { return __uint_as_float(u << 16); }
__device__ __forceinline__ float bfhi(unsigned u) { return __uint_as_float(u & 0xffff0000u); }
__device__ __forceinline__ float bf2f(ushort u) { return __uint_as_float(((unsigned)u) << 16); }
__device__ __forceinline__ ushort f2b(float f) {  // RNE
  unsigned u = __float_as_uint(f);
  u += 0x7fff + ((u >> 16) & 1);
  return (ushort)(u >> 16);
}

// ---------- CSR build (key = dst*8 + rel) ----------

__global__ __launch_bounds__(256) void count_kernel(const int* __restrict__ ei,
                                                    const int* __restrict__ et,
                                                    int* __restrict__ cnt) {
  int t = blockIdx.x * 256 + threadIdx.x;
  if (t < EE) {
    int key = ei[EE + t] * NREL + et[t];
    atomicAdd(&cnt[key], 1);
  }
}

__global__ __launch_bounds__(256) void scan1_kernel(const int* __restrict__ cnt,
                                                    int* __restrict__ off,
                                                    int* __restrict__ bsum) {
  __shared__ int s[256];
  const int tid = threadIdx.x;
  const int i = blockIdx.x * 256 + tid;
  int v = (i < NBUCK) ? cnt[i] : 0;
  s[tid] = v;
  __syncthreads();
#pragma unroll
  for (int o = 1; o < 256; o <<= 1) {
    int t2 = (tid >= o) ? s[tid - o] : 0;
    __syncthreads();
    s[tid] += t2;
    __syncthreads();
  }
  if (i < NBUCK) off[i] = s[tid] - v;
  if (tid == 255) bsum[blockIdx.x] = s[255];
}

__global__ __launch_bounds__(256) void scan2_kernel(const int* __restrict__ bsum,
                                                    int* __restrict__ bpre) {
  __shared__ int s[256];
  __shared__ int carry;
  const int tid = threadIdx.x;
  if (tid == 0) carry = 0;
  __syncthreads();
  const int chunks = (SCAN_NB + 255) / 256;
  for (int c = 0; c < chunks; c++) {
    int idx = c * 256 + tid;
    int v = (idx < SCAN_NB) ? bsum[idx] : 0;
    s[tid] = v;
    __syncthreads();
#pragma unroll
    for (int o = 1; o < 256; o <<= 1) {
      int t2 = (tid >= o) ? s[tid - o] : 0;
      __syncthreads();
      s[tid] += t2;
      __syncthreads();
    }
    if (idx < SCAN_NB) bpre[idx] = carry + s[tid] - v;
    __syncthreads();
    if (tid == 255) carry += s[255];
    __syncthreads();
  }
}

// finalizes off, fills cursor, zeroes the degree-bin histogram
__global__ __launch_bounds__(256) void scan3_kernel(int* __restrict__ off,
                                                    const int* __restrict__ bpre,
                                                    int* __restrict__ cursor,
                                                    int* __restrict__ hist) {
  int i = blockIdx.x * 256 + threadIdx.x;
  if (i < NBUCK) {
    int o = off[i] + bpre[i >> 8];
    off[i] = o;
    cursor[i] = o;
  }
  if (i < NBIN) hist[i] = 0;
  if (i == 0) off[NBUCK] = EE;
}

// rec word0 = src | rel<<16 ; word1 = ew/cnt (pre-divided mean scale)
__global__ __launch_bounds__(256) void bucket_kernel(const int* __restrict__ ei,
                                                     const int* __restrict__ et,
                                                     const float* __restrict__ ew,
                                                     const int* __restrict__ cnt,
                                                     int* __restrict__ cursor,
                                                     uint2* __restrict__ rec) {
  int e = blockIdx.x * 256 + threadIdx.x;
  if (e >= EE) return;
  int r = et[e];
  int key = ei[EE + e] * NREL + r;
  float scale = ew[e] / fmaxf((float)cnt[key], 1.0f);
  int pos = atomicAdd(&cursor[key], 1);
  rec[pos] = make_uint2((unsigned)ei[e] | ((unsigned)r << 16), __float_as_uint(scale));
}

// ---------- node-degree counting sort -> vqueue ----------

__global__ __launch_bounds__(256) void vhist_kernel(const int* __restrict__ off,
                                                    int* __restrict__ hist) {
  __shared__ int lh[NBIN];
  const int tid = threadIdx.x;
  if (tid < NBIN) lh[tid] = 0;
  __syncthreads();
  int v = blockIdx.x * 256 + tid;
  if (v < NN) {
    int deg = off[v * NREL + NREL] - off[v * NREL];
    atomicAdd(&lh[min(deg, NBIN - 1)], 1);
  }
  __syncthreads();
  if (tid < NBIN && lh[tid] > 0) atomicAdd(&hist[tid], lh[tid]);
}

__global__ __launch_bounds__(256) void scan64_kernel(const int* __restrict__ hist,
                                                     int* __restrict__ binCur) {
  __shared__ int s[NBIN];
  const int tid = threadIdx.x;
  if (tid < NBIN) s[tid] = hist[tid];
  __syncthreads();
#pragma unroll
  for (int o = 1; o < NBIN; o <<= 1) {
    int t2 = (tid < NBIN && tid >= o) ? s[tid - o] : 0;
    __syncthreads();
    if (tid < NBIN) s[tid] += t2;
    __syncthreads();
  }
  if (tid < NBIN) binCur[tid] = s[tid] - hist[tid];
}

__global__ __launch_bounds__(256) void vqbuild_kernel(const int* __restrict__ off,
                                                      int* __restrict__ binCur,
                                                      int* __restrict__ vqueue) {
  __shared__ int lh[NBIN];
  __shared__ int lbase[NBIN];
  const int tid = threadIdx.x;
  const int v = blockIdx.x * 256 + tid;
  int bin = -1, lpos = 0;
  if (tid < NBIN) lh[tid] = 0;
  __syncthreads();
  if (v < NN) {
    int deg = off[v * NREL + NREL] - off[v * NREL];
    bin = min(deg, NBIN - 1);
    lpos = atomicAdd(&lh[bin], 1);
  }
  __syncthreads();
  if (tid < NBIN && lh[tid] > 0) lbase[tid] = atomicAdd(&binCur[tid], lh[tid]);
  __syncthreads();
  if (bin >= 0) vqueue[lbase[bin] + lpos] = v;
}

// ---------- pack x (bf16) + W1Tc + W2T ----------
// W1Tc[n*1024 + r*128 + k] = bf16(W1[r][k][n]); W2T[j*128 + k] = bf16(W2[j>>4][k][j&15])
#define XQ (NN * DD / 4)
__global__ __launch_bounds__(256) void pack_kernel(const float* __restrict__ x,
                                                   const float* __restrict__ W1,
                                                   const float* __restrict__ W2,
                                                   ushort* __restrict__ xb,
                                                   ushort* __restrict__ W1Tc,
                                                   ushort* __restrict__ W2T) {
  int t = blockIdx.x * 256 + threadIdx.x;
  if (t < XQ) {
    float4 v = *(const float4*)&x[(size_t)t * 4];
    *(ushort4*)&xb[(size_t)t * 4] = make_ushort4(f2b(v.x), f2b(v.y), f2b(v.z), f2b(v.w));
  } else if (t < XQ + NREL * DD * DD) {
    int t2 = t - XQ;
    int n = t2 >> 10, r = (t2 >> 7) & 7, k = t2 & 127;
    W1Tc[t2] = f2b(W1[r * 16384 + k * 128 + n]);
  } else if (t < XQ + NREL * DD * DD + DD * DD) {
    int t2 = t - XQ - NREL * DD * DD;
    int j = t2 >> 7, k = t2 & 127;
    W2T[t2] = f2b(W2[(j >> 4) * (DD * NCLS) + k * NCLS + (j & 15)]);
  }
}

// ---------- fused layer1+layer2 ----------
// Single-pass gather: each node's edge list is contiguous AND rel-sorted (CSR key
// dst*8+rel). 16 threads/node x 8 cols walk ALL the node's edges once (trip count
// = total degree, equalized by vqueue sort), accumulating g[8] in registers and
// flushing to the LDS A-tile slot [node][rel*128+col] on rel change. No barriers
// during the gather; 4 edges in flight per lane. Then ONE K=1024 MFMA sweep
// (A 32x1024 @ W1cat 1024x128), fused relu + layer-2 GEMM, bf16 H2 out.
// Accumulation order identical to the per-relation version -> bit-identical.
__global__ __launch_bounds__(512) void fused1_kernel(const int* __restrict__ off,
                                                     const uint2* __restrict__ rec,
                                                     const ushort* __restrict__ xb,
                                                     const ushort* __restrict__ W1Tc,
                                                     const ushort* __restrict__ W2T,
                                                     const int* __restrict__ vqueue,
                                                     ushort* __restrict__ H2) {
  __shared__ ushort At[TNODES * 1032];       // 66048 B, row stride 1032 (516 words = 4 mod 32 banks)
  __shared__ uint2 recL[TNODES * RECCAP];    // 10240 B
  __shared__ int vids[TNODES];               // total 76416 B -> 2 blocks/CU
  const int tid = threadIdx.x;
  const int wave = tid >> 6, lane = tid & 63;
  const int lm = lane & 15, lkb = (lane >> 4) * 8;
  const int gn = tid >> 4;        // node slot 0..31
  const int gj = tid & 15;        // 16 threads/node
  const int gc = gj * 8;          // 8 cols (one uint4) per thread
  const int qi = blockIdx.x * TNODES + gn;
  const int v = (qi < NN) ? vqueue[qi] : -1;
  if (gj == 0) vids[gn] = v;

  int s = 0, e = 0;
  if (v >= 0) {
    s = off[v * 8];
    e = off[v * 8 + 8];
  }

  // zero the A-tile (only the 1024 real cols; pad cols never read)
  {
    const int zr = tid >> 4, zc = (tid & 15) * 64;
#pragma unroll
    for (int j = 0; j < 8; j++)
      *(uint4*)&At[zr * 1032 + zc + j * 8] = make_uint4(0u, 0u, 0u, 0u);
  }
  // coalesced rec preload (16 threads/node); broadcast-read later (same addr per node)
  const int rbase = gn * RECCAP;
  {
    int dcap = min(e - s, RECCAP);
    for (int i = gj; i < dcap; i += 16) recL[rbase + i] = rec[s + i];
  }
  __syncthreads();

#define GETR(q, ii)                                             \
  do {                                                          \
    int _ri = (ii) - s;                                         \
    q = (_ri < RECCAP) ? recL[rbase + _ri] : rec[(ii)];         \
  } while (0)
#define LOADE(ii, hv, scv, rv)                                  \
  do {                                                          \
    uint2 _q;                                                   \
    GETR(_q, (ii));                                             \
    scv = __uint_as_float(_q.y);                                \
    rv = (int)(_q.x >> 16);                                     \
    hv = *(const uint4*)&xb[(size_t)(_q.x & 0xffff) * DD + gc]; \
  } while (0)
#define FLUSH()                                                   \
  do {                                                            \
    uint4 _u;                                                     \
    _u.x = (unsigned)f2b(g[0]) | ((unsigned)f2b(g[1]) << 16);     \
    _u.y = (unsigned)f2b(g[2]) | ((unsigned)f2b(g[3]) << 16);     \
    _u.z = (unsigned)f2b(g[4]) | ((unsigned)f2b(g[5]) << 16);     \
    _u.w = (unsigned)f2b(g[6]) | ((unsigned)f2b(g[7]) << 16);     \
    *(uint4*)&At[gn * 1032 + cur * 128 + gc] = _u;                \
  } while (0)
#define PROC(hv, scv, rv)                                         \
  do {                                                            \
    if (rv != cur) {                                              \
      if (cur >= 0) FLUSH();                                      \
      cur = rv;                                                   \
      g[0] = g[1] = g[2] = g[3] = g[4] = g[5] = g[6] = g[7] = 0.f;\
    }                                                             \
    g[0] = fmaf(scv, bflo(hv.x), g[0]);                           \
    g[1] = fmaf(scv, bfhi(hv.x), g[1]);                           \
    g[2] = fmaf(scv, bflo(hv.y), g[2]);                           \
    g[3] = fmaf(scv, bfhi(hv.y), g[3]);                           \
    g[4] = fmaf(scv, bflo(hv.z), g[4]);                           \
    g[5] = fmaf(scv, bfhi(hv.z), g[5]);                           \
    g[6] = fmaf(scv, bflo(hv.w), g[6]);                           \
    g[7] = fmaf(scv, bfhi(hv.w), g[7]);                           \
  } while (0)

  {
    float g[8];
    g[0] = g[1] = g[2] = g[3] = g[4] = g[5] = g[6] = g[7] = 0.f;
    int cur = -1;
    int i = s;
    for (; i + 4 <= e; i += 4) {
      uint4 h0, h1, h2, h3;
      float s0, s1, s2, s3;
      int r0, r1, r2, r3;
      LOADE(i, h0, s0, r0);
      LOADE(i + 1, h1, s1, r1);
      LOADE(i + 2, h2, s2, r2);
      LOADE(i + 3, h3, s3, r3);
      PROC(h0, s0, r0);
      PROC(h1, s1, r1);
      PROC(h2, s2, r2);
      PROC(h3, s3, r3);
    }
    for (; i < e; i++) {
      uint4 h;
      float sc;
      int rl;
      LOADE(i, h, sc, rl);
      PROC(h, sc, rl);
    }
    if (cur >= 0) FLUSH();
  }
#undef PROC
#undef FLUSH
#undef LOADE
#undef GETR
  __syncthreads();

  // ---- layer-1 GEMM: K=1024 sweep, wave owns out-cols [wave*16, wave*16+16) ----
  f32x4 a0 = (f32x4){0.f, 0.f, 0.f, 0.f};
  f32x4 a1 = (f32x4){0.f, 0.f, 0.f, 0.f};
#pragma unroll 8
  for (int kk = 0; kk < 1024; kk += 32) {
    short8 b = *(const short8*)&W1Tc[(size_t)(wave * 16 + lm) * 1024 + kk + lkb];
    short8 x0 = *(const short8*)&At[lm * 1032 + kk + lkb];
    short8 x1 = *(const short8*)&At[(16 + lm) * 1032 + kk + lkb];
    a0 = __builtin_amdgcn_mfma_f32_16x16x32_bf16(x0, b, a0, 0, 0, 0);
    a1 = __builtin_amdgcn_mfma_f32_16x16x32_bf16(x1, b, a1, 0, 0, 0);
  }
  __syncthreads();  // At reads complete before reuse as A2

  // ---- epilogue 1: relu -> bf16 A2 tile (reuse At memory, stride 136) ----
  const int rquad = (lane >> 4) * 4;
#pragma unroll
  for (int i2 = 0; i2 < 4; i2++) {
    At[(rquad + i2) * 136 + wave * 16 + lm] = f2b(fmaxf(a0[i2], 0.f));
    At[(16 + rquad + i2) * 136 + wave * 16 + lm] = f2b(fmaxf(a1[i2], 0.f));
  }
  __syncthreads();

  // ---- layer-2 GEMM on the in-LDS A2 tile (W2T from L2) ----
  f32x4 c0 = (f32x4){0.f, 0.f, 0.f, 0.f};
  f32x4 c1 = (f32x4){0.f, 0.f, 0.f, 0.f};
#pragma unroll
  for (int k0 = 0; k0 < 128; k0 += 32) {
    short8 b = *(const short8*)&W2T[(size_t)(wave * 16 + lm) * DD + k0 + lkb];
    short8 x0 = *(const short8*)&At[lm * 136 + k0 + lkb];
    short8 x1 = *(const short8*)&At[(16 + lm) * 136 + k0 + lkb];
    c0 = __builtin_amdgcn_mfma_f32_16x16x32_bf16(x0, b, c0, 0, 0, 0);
    c1 = __builtin_amdgcn_mfma_f32_16x16x32_bf16(x1, b, c1, 0, 0, 0);
  }
  __syncthreads();
#pragma unroll
  for (int i2 = 0; i2 < 4; i2++) {
    At[(rquad + i2) * 136 + wave * 16 + lm] = f2b(c0[i2]);
    At[(16 + rquad + i2) * 136 + wave * 16 + lm] = f2b(c1[i2]);
  }
  __syncthreads();
  {
    int row = tid >> 4, c8 = (tid & 15) * 8;
    int gr = vids[row];
    if (gr >= 0) *(uint4*)&H2[(size_t)gr * DD + c8] = *(const uint4*)&At[row * 136 + c8];
  }
}

// ---------- gather2 + log_softmax ----------
// 16 nodes/block from degree-sorted queue; 16 lanes/node walk the node's single
// contiguous edge range (rel tag in rec), 2 edges in flight; rec range preloaded
// into LDS (coalesced) to shorten the rec->H2 dependent chain; fused log-softmax.
__global__ __launch_bounds__(256) void gather2_kernel(const int* __restrict__ off,
                                                      const uint2* __restrict__ rec,
                                                      const ushort* __restrict__ H2,
                                                      const int* __restrict__ vqueue,
                                                      float* __restrict__ out) {
  __shared__ uint2 recL[16 * RECCAP];  // 5120 B
  const int tid = threadIdx.x;
  const int g = tid >> 4, c = tid & 15;
  const int qi = blockIdx.x * 16 + g;
  int v = 0, s = 0, e = 0;
  if (qi < NN) {
    v = vqueue[qi];
    s = off[v * NREL];
    e = off[v * NREL + NREL];
  }
  const int rbase = g * RECCAP;
  {
    int dcap = min(e - s, RECCAP);
    for (int i = c; i < dcap; i += 16) recL[rbase + i] = rec[s + i];
  }
  __syncthreads();

#define GETREC2(qdst, ii)                                       \
  do {                                                          \
    int _ri = (ii) - s;                                         \
    if (_ri < RECCAP) qdst = recL[rbase + _ri];                 \
    else qdst = rec[(ii)];                                      \
  } while (0)

  float acc = 0.f;
  if (qi < NN) {
    int j = s;
    for (; j + 2 <= e; j += 2) {
      uint2 q0, q1;
      GETREC2(q0, j);
      GETREC2(q1, j + 1);
      ushort h0 = H2[(size_t)(q0.x & 0xffff) * DD + (q0.x >> 16) * NCLS + c];
      ushort h1 = H2[(size_t)(q1.x & 0xffff) * DD + (q1.x >> 16) * NCLS + c];
      acc = fmaf(__uint_as_float(q0.y), bf2f(h0), acc);
      acc = fmaf(__uint_as_float(q1.y), bf2f(h1), acc);
    }
    if (j < e) {
      uint2 q;
      GETREC2(q, j);
      acc = fmaf(__uint_as_float(q.y),
                 bf2f(H2[(size_t)(q.x & 0xffff) * DD + (q.x >> 16) * NCLS + c]), acc);
    }
  }
#undef GETREC2
  float m = acc;
#pragma unroll
  for (int mask = 8; mask >= 1; mask >>= 1) m = fmaxf(m, __shfl_xor(m, mask, 16));
  float ex = expf(acc - m);
#pragma unroll
  for (int mask = 8; mask >= 1; mask >>= 1) ex += __shfl_xor(ex, mask, 16);
  if (qi < NN) out[(size_t)v * NCLS + c] = acc - m - logf(ex);
}

extern "C" void kernel_launch(void* const* d_in, const int* in_sizes, int n_in,
                              void* d_out, int out_size, void* d_ws, size_t ws_size,
                              hipStream_t stream) {
  const float* x  = (const float*)d_in[0];
  const int*   ei = (const int*)d_in[1];
  const int*   et = (const int*)d_in[2];
  const float* ew = (const float*)d_in[3];
  const float* W1 = (const float*)d_in[4];
  const float* W2 = (const float*)d_in[5];
  float* out = (float*)d_out;
  float* ws = (float*)d_ws;

  // workspace layout (float-unit offsets; ~36 MB)
  int*    cnt    = (int*)ws;                    // 400000
  int*    off    = (int*)(ws + 400000);         // 400001 (+pad)
  int*    bsum   = (int*)(ws + 800004);         // 1563 (+pad)
  int*    bpre   = (int*)(ws + 801568);         // 1563 (+pad)
  int*    cursor = (int*)(ws + 803132);         // 400000
  int*    hist   = (int*)(ws + 1203132);        // 64
  int*    binCur = (int*)(ws + 1203196);        // 64
  int*    vqueue = (int*)(ws + 1203260);        // 50000
  uint2*  rec    = (uint2*)(ws + 1253260);      // 640000 uint2
  ushort* xb     = (ushort*)(ws + 2533260);     // NN*DD bf16
  ushort* W1Tc   = (ushort*)(ws + 5733260);     // 128*1024 bf16
  ushort* W2T    = (ushort*)(ws + 5798796);     // 128*128 bf16
  ushort* H2     = (ushort*)(ws + 5806988);     // NN*DD bf16

  hipMemsetAsync(cnt, 0, (size_t)NBUCK * sizeof(int), stream);

  count_kernel<<<(EE + 255) / 256, 256, 0, stream>>>(ei, et, cnt);
  scan1_kernel<<<SCAN_NB, 256, 0, stream>>>(cnt, off, bsum);
  scan2_kernel<<<1, 256, 0, stream>>>(bsum, bpre);
  scan3_kernel<<<SCAN_NB, 256, 0, stream>>>(off, bpre, cursor, hist);
  bucket_kernel<<<(EE + 255) / 256, 256, 0, stream>>>(ei, et, ew, cnt, cursor, rec);

  vhist_kernel<<<(NN + 255) / 256, 256, 0, stream>>>(off, hist);
  scan64_kernel<<<1, 256, 0, stream>>>(hist, binCur);
  vqbuild_kernel<<<(NN + 255) / 256, 256, 0, stream>>>(off, binCur, vqueue);

  const int packN = XQ + NREL * DD * DD + DD * DD;
  pack_kernel<<<(packN + 255) / 256, 256, 0, stream>>>(x, W1, W2, xb, W1Tc, W2T);

  fused1_kernel<<<(NN + TNODES - 1) / TNODES, 512, 0, stream>>>(off, rec, xb, W1Tc, W2T, vqueue, H2);
  gather2_kernel<<<(NN + 15) / 16, 256, 0, stream>>>(off, rec, H2, vqueue, out);
}

// Round 3
// 257.116 us; speedup vs baseline: 1.0927x; 1.0927x over previous
//
#include <hip/hip_runtime.h>
#include <hip/hip_bf16.h>
#include <math.h>

#define NN 50000
#define EE 640000
#define DD 128
#define NREL 8
#define NCLS 16
#define NBUCK (NREL * NN)              // 400000 buckets, key = dst*8 + rel (dst-major)
#define SCAN_NB ((NBUCK + 255) / 256)  // 1563
#define RECCAP 40                      // max cached recs/node in LDS

typedef __attribute__((ext_vector_type(8))) short short8;   // 8 bf16 = 4 VGPRs
typedef __attribute__((ext_vector_type(4))) float f32x4;    // MFMA acc

__device__ __forceinline__ float bflo(unsigned u) { return __uint_as_float(u << 16); }
__device__ __forceinline__ float bfhi(unsigned u) { return __uint_as_float(u & 0xffff0000u); }
__device__ __forceinline__ float bf2f(ushort u) { return __uint_as_float(((unsigned)u) << 16); }
__device__ __forceinline__ ushort f2b(float f) {  // RNE
  unsigned u = __float_as_uint(f);
  u += 0x7fff + ((u >> 16) & 1);
  return (ushort)(u >> 16);
}

// ---------- merged count (CSR histogram) + pack (x->bf16, W1Tc, W2T) ----------
// W1Tc[n*1024 + r*128 + k] = bf16(W1[r][k][n]); W2T[j*128 + k] = bf16(W2[j>>4][k][j&15])
#define XQ (NN * DD / 4)
#define PACKN (XQ + NREL * DD * DD + DD * DD)
__global__ __launch_bounds__(256) void countpack_kernel(const int* __restrict__ ei,
                                                        const int* __restrict__ et,
                                                        const float* __restrict__ x,
                                                        const float* __restrict__ W1,
                                                        const float* __restrict__ W2,
                                                        int* __restrict__ cnt,
                                                        ushort* __restrict__ xb,
                                                        ushort* __restrict__ W1Tc,
                                                        ushort* __restrict__ W2T) {
  int t = blockIdx.x * 256 + threadIdx.x;
  if (t < EE) {
    int key = ei[EE + t] * NREL + et[t];
    atomicAdd(&cnt[key], 1);
  }
  if (t < XQ) {
    float4 v = *(const float4*)&x[(size_t)t * 4];
    *(ushort4*)&xb[(size_t)t * 4] = make_ushort4(f2b(v.x), f2b(v.y), f2b(v.z), f2b(v.w));
  } else if (t < XQ + NREL * DD * DD) {
    int t2 = t - XQ;
    int n = t2 >> 10, r = (t2 >> 7) & 7, k = t2 & 127;
    W1Tc[t2] = f2b(W1[r * 16384 + k * 128 + n]);
  } else if (t < PACKN) {
    int t2 = t - XQ - NREL * DD * DD;
    int j = t2 >> 7, k = t2 & 127;
    W2T[t2] = f2b(W2[(j >> 4) * (DD * NCLS) + k * NCLS + (j & 15)]);
  }
}

__global__ __launch_bounds__(256) void scan1_kernel(const int* __restrict__ cnt,
                                                    int* __restrict__ off,
                                                    int* __restrict__ bsum) {
  __shared__ int s[256];
  const int tid = threadIdx.x;
  const int i = blockIdx.x * 256 + tid;
  int v = (i < NBUCK) ? cnt[i] : 0;
  s[tid] = v;
  __syncthreads();
#pragma unroll
  for (int o = 1; o < 256; o <<= 1) {
    int t2 = (tid >= o) ? s[tid - o] : 0;
    __syncthreads();
    s[tid] += t2;
    __syncthreads();
  }
  if (i < NBUCK) off[i] = s[tid] - v;
  if (tid == 255) bsum[blockIdx.x] = s[255];
}

// single-wave shuffle scan over the 1563 block sums (no barriers)
__global__ __launch_bounds__(64) void scan2_kernel(const int* __restrict__ bsum,
                                                   int* __restrict__ bpre) {
  const int lane = threadIdx.x;
  int carry = 0;
  for (int base = 0; base < SCAN_NB; base += 64) {
    int idx = base + lane;
    int own = (idx < SCAN_NB) ? bsum[idx] : 0;
    int v = own;
#pragma unroll
    for (int o = 1; o < 64; o <<= 1) {
      int t = __shfl_up(v, o, 64);
      if (lane >= o) v += t;
    }
    if (idx < SCAN_NB) bpre[idx] = carry + v - own;
    carry += __shfl(v, 63, 64);
  }
}

// finalizes off, fills cursor
__global__ __launch_bounds__(256) void scan3_kernel(int* __restrict__ off,
                                                    const int* __restrict__ bpre,
                                                    int* __restrict__ cursor) {
  int i = blockIdx.x * 256 + threadIdx.x;
  if (i < NBUCK) {
    int o = off[i] + bpre[i >> 8];
    off[i] = o;
    cursor[i] = o;
  }
  if (i == 0) off[NBUCK] = EE;
}

// rec word0 = src | rel<<16 ; word1 = ew/cnt (pre-divided mean scale)
__global__ __launch_bounds__(256) void bucket_kernel(const int* __restrict__ ei,
                                                     const int* __restrict__ et,
                                                     const float* __restrict__ ew,
                                                     const int* __restrict__ cnt,
                                                     int* __restrict__ cursor,
                                                     uint2* __restrict__ rec) {
  int e = blockIdx.x * 256 + threadIdx.x;
  if (e >= EE) return;
  int r = et[e];
  int key = ei[EE + e] * NREL + r;
  float scale = ew[e] / fmaxf((float)cnt[key], 1.0f);
  int pos = atomicAdd(&cursor[key], 1);
  rec[pos] = make_uint2((unsigned)ei[e] | ((unsigned)r << 16), __float_as_uint(scale));
}

// ---------- fused layer1+layer2: H2 = bf16( relu(gather(x) @ W1cat) @ W2T^T ) ----------
// R1 structure (proven 85us, fabric-bound): 64 nodes/block, 8 thr/node x 16 cols,
// per-relation walk with 2 edges in flight; rec preloaded to LDS (coalesced);
// 8 waves each own 16 out-cols; layer-2 GEMM fused on the in-LDS A2 tile.
__global__ __launch_bounds__(512) void fused1_kernel(const int* __restrict__ off,
                                                     const uint2* __restrict__ rec,
                                                     const ushort* __restrict__ xb,
                                                     const ushort* __restrict__ W1Tc,
                                                     const ushort* __restrict__ W2T,
                                                     ushort* __restrict__ H2) {
  __shared__ ushort AsU[64 * 136];         // 17408 B
  __shared__ uint2 recL[64 * RECCAP];      // 20480 B  (total 37888 B -> 4 blocks/CU)
  const int tid = threadIdx.x;
  const int m0 = blockIdx.x * 64;
  const int wave = tid >> 6, lane = tid & 63;
  const int lm = lane & 15, lkb = (lane >> 4) * 8;
  const int gn = tid >> 3;          // gather: node slot 0..63
  const int gj = tid & 7;           // gather: 8 threads/node
  const int gc = gj * 16;           // gather: col base (16 cols)
  const int v = m0 + gn;

  // hoist the node's 9 contiguous offsets (dst-major key)
  int offv[9];
  if (v < NN) {
    int4 o0 = *(const int4*)&off[v * 8];
    int4 o1 = *(const int4*)&off[v * 8 + 4];
    offv[0] = o0.x; offv[1] = o0.y; offv[2] = o0.z; offv[3] = o0.w;
    offv[4] = o1.x; offv[5] = o1.y; offv[6] = o1.z; offv[7] = o1.w;
    offv[8] = off[v * 8 + 8];
  } else {
#pragma unroll
    for (int i = 0; i < 9; i++) offv[i] = 0;
  }
  const int b0 = offv[0];
  const int rbase = gn * RECCAP;
  {
    int dcap = min(offv[8] - b0, RECCAP);
    for (int i = gj; i < dcap; i += 8) recL[rbase + i] = rec[b0 + i];
  }
  // recL visibility for r=0 is guaranteed by the r-loop's leading __syncthreads

#define GETREC(qdst, ii)                                        \
  do {                                                          \
    int _ri = (ii) - b0;                                        \
    if (_ri < RECCAP) qdst = recL[rbase + _ri];                 \
    else qdst = rec[(ii)];                                      \
  } while (0)

  f32x4 acc[4];
#pragma unroll
  for (int m = 0; m < 4; m++) acc[m] = (f32x4){0.f, 0.f, 0.f, 0.f};

#pragma unroll
  for (int r = 0; r < NREL; r++) {
    __syncthreads();  // previous chunk's AsU reads complete (and r=0: recL ready)
    // register gather, 2 edges in flight, 16 cols (2 uint4) per edge
    float g[16];
#pragma unroll
    for (int j = 0; j < 16; j++) g[j] = 0.f;
    {
      int s = offv[r], e = offv[r + 1];
      int i = s;
      for (; i + 2 <= e; i += 2) {
        uint2 q0, q1;
        GETREC(q0, i);
        GETREC(q1, i + 1);
        float sc0 = __uint_as_float(q0.y), sc1 = __uint_as_float(q1.y);
        const ushort* xr0 = &xb[(size_t)(q0.x & 0xffff) * DD + gc];
        const ushort* xr1 = &xb[(size_t)(q1.x & 0xffff) * DD + gc];
        uint4 h0[2], h1[2];
#pragma unroll
        for (int jj = 0; jj < 2; jj++) h0[jj] = *(const uint4*)&xr0[jj * 8];
#pragma unroll
        for (int jj = 0; jj < 2; jj++) h1[jj] = *(const uint4*)&xr1[jj * 8];
#pragma unroll
        for (int jj = 0; jj < 2; jj++) {
          float* gg = &g[jj * 8];
          gg[0] = fmaf(sc0, bflo(h0[jj].x), gg[0]);
          gg[1] = fmaf(sc0, bfhi(h0[jj].x), gg[1]);
          gg[2] = fmaf(sc0, bflo(h0[jj].y), gg[2]);
          gg[3] = fmaf(sc0, bfhi(h0[jj].y), gg[3]);
          gg[4] = fmaf(sc0, bflo(h0[jj].z), gg[4]);
          gg[5] = fmaf(sc0, bfhi(h0[jj].z), gg[5]);
          gg[6] = fmaf(sc0, bflo(h0[jj].w), gg[6]);
          gg[7] = fmaf(sc0, bfhi(h0[jj].w), gg[7]);
          gg[0] = fmaf(sc1, bflo(h1[jj].x), gg[0]);
          gg[1] = fmaf(sc1, bfhi(h1[jj].x), gg[1]);
          gg[2] = fmaf(sc1, bflo(h1[jj].y), gg[2]);
          gg[3] = fmaf(sc1, bfhi(h1[jj].y), gg[3]);
          gg[4] = fmaf(sc1, bflo(h1[jj].z), gg[4]);
          gg[5] = fmaf(sc1, bfhi(h1[jj].z), gg[5]);
          gg[6] = fmaf(sc1, bflo(h1[jj].w), gg[6]);
          gg[7] = fmaf(sc1, bfhi(h1[jj].w), gg[7]);
        }
      }
      if (i < e) {
        uint2 q;
        GETREC(q, i);
        float sc = __uint_as_float(q.y);
        const ushort* xr = &xb[(size_t)(q.x & 0xffff) * DD + gc];
#pragma unroll
        for (int jj = 0; jj < 2; jj++) {
          uint4 h = *(const uint4*)&xr[jj * 8];
          float* gg = &g[jj * 8];
          gg[0] = fmaf(sc, bflo(h.x), gg[0]);
          gg[1] = fmaf(sc, bfhi(h.x), gg[1]);
          gg[2] = fmaf(sc, bflo(h.y), gg[2]);
          gg[3] = fmaf(sc, bfhi(h.y), gg[3]);
          gg[4] = fmaf(sc, bflo(h.z), gg[4]);
          gg[5] = fmaf(sc, bfhi(h.z), gg[5]);
          gg[6] = fmaf(sc, bflo(h.w), gg[6]);
          gg[7] = fmaf(sc, bfhi(h.w), gg[7]);
        }
      }
    }
#pragma unroll
    for (int jj = 0; jj < 2; jj++) {
      uint4 u;
      u.x = (unsigned)f2b(g[jj * 8 + 0]) | ((unsigned)f2b(g[jj * 8 + 1]) << 16);
      u.y = (unsigned)f2b(g[jj * 8 + 2]) | ((unsigned)f2b(g[jj * 8 + 3]) << 16);
      u.z = (unsigned)f2b(g[jj * 8 + 4]) | ((unsigned)f2b(g[jj * 8 + 5]) << 16);
      u.w = (unsigned)f2b(g[jj * 8 + 6]) | ((unsigned)f2b(g[jj * 8 + 7]) << 16);
      *(uint4*)&AsU[gn * 136 + gc + jj * 8] = u;
    }
    __syncthreads();
    // MFMA: wave owns out-cols [wave*16, wave*16+16); B fragment from L2
#pragma unroll
    for (int k0 = 0; k0 < 128; k0 += 32) {
      short8 b = *(const short8*)&W1Tc[(size_t)(wave * 16 + lm) * 1024 + r * 128 + k0 + lkb];
      short8 a[4];
#pragma unroll
      for (int m = 0; m < 4; m++)
        a[m] = *(const short8*)&AsU[(m * 16 + lm) * 136 + k0 + lkb];
#pragma unroll
      for (int m = 0; m < 4; m++)
        acc[m] = __builtin_amdgcn_mfma_f32_16x16x32_bf16(a[m], b, acc[m], 0, 0, 0);
    }
  }
#undef GETREC

  // ---- epilogue 1: relu -> bf16 A2 tile in LDS ----
  __syncthreads();
  const int rquad = (lane >> 4) * 4;
#pragma unroll
  for (int m = 0; m < 4; m++)
#pragma unroll
    for (int i = 0; i < 4; i++)
      AsU[(m * 16 + rquad + i) * 136 + wave * 16 + lm] = f2b(fmaxf(acc[m][i], 0.f));
  __syncthreads();

  // ---- layer-2 GEMM on the in-LDS A2 tile (W2T from L2) ----
  f32x4 acc2[4];
#pragma unroll
  for (int m = 0; m < 4; m++) acc2[m] = (f32x4){0.f, 0.f, 0.f, 0.f};
#pragma unroll
  for (int k0 = 0; k0 < 128; k0 += 32) {
    short8 b = *(const short8*)&W2T[(size_t)(wave * 16 + lm) * DD + k0 + lkb];
    short8 a[4];
#pragma unroll
    for (int m = 0; m < 4; m++)
      a[m] = *(const short8*)&AsU[(m * 16 + lm) * 136 + k0 + lkb];
#pragma unroll
    for (int m = 0; m < 4; m++)
      acc2[m] = __builtin_amdgcn_mfma_f32_16x16x32_bf16(a[m], b, acc2[m], 0, 0, 0);
  }
  __syncthreads();
#pragma unroll
  for (int m = 0; m < 4; m++)
#pragma unroll
    for (int i = 0; i < 4; i++)
      AsU[(m * 16 + rquad + i) * 136 + wave * 16 + lm] = f2b(acc2[m][i]);
  __syncthreads();
#pragma unroll
  for (int i = 0; i < 2; i++) {
    int seg = tid + i * 512;
    int row = seg >> 4, c8 = (seg & 15) * 8;
    int gr = m0 + row;
    if (gr < NN) *(uint4*)&H2[(size_t)gr * DD + c8] = *(const uint4*)&AsU[row * 136 + c8];
  }
}

// ---------- gather2 + log_softmax ----------
// 8 consecutive nodes/block, 32 lanes/node: even/odd edges processed by the two
// 16-lane halves in parallel, 2-deep unroll (4 edges in flight/node). rec preload
// to LDS (near-contiguous across consecutive nodes); halves combined via
// shfl_xor(16); fused log-softmax; coalesced out store.
__global__ __launch_bounds__(256) void gather2_kernel(const int* __restrict__ off,
                                                      const uint2* __restrict__ rec,
                                                      const ushort* __restrict__ H2,
                                                      float* __restrict__ out) {
  __shared__ uint2 recL[8 * RECCAP];  // 2560 B
  const int tid = threadIdx.x;
  const int g = tid >> 5;          // node slot 0..7
  const int sub = tid & 31;
  const int j = sub >> 4;          // edge parity
  const int c = sub & 15;          // class
  const int v = blockIdx.x * 8 + g;
  int s = 0, e = 0;
  if (v < NN) {
    s = off[v * NREL];
    e = off[v * NREL + NREL];
  }
  const int rbase = g * RECCAP;
  {
    int dcap = min(e - s, RECCAP);
    for (int i = sub; i < dcap; i += 32) recL[rbase + i] = rec[s + i];
  }
  __syncthreads();

#define GETREC2(qdst, ii)                                       \
  do {                                                          \
    int _ri = (ii) - s;                                         \
    if (_ri < RECCAP) qdst = recL[rbase + _ri];                 \
    else qdst = rec[(ii)];                                      \
  } while (0)

  float acc = 0.f;
  if (v < NN) {
    int i = s + j;
    for (; i + 2 < e; i += 4) {
      uint2 q0, q1;
      GETREC2(q0, i);
      GETREC2(q1, i + 2);
      ushort h0 = H2[(size_t)(q0.x & 0xffff) * DD + (q0.x >> 16) * NCLS + c];
      ushort h1 = H2[(size_t)(q1.x & 0xffff) * DD + (q1.x >> 16) * NCLS + c];
      acc = fmaf(__uint_as_float(q0.y), bf2f(h0), acc);
      acc = fmaf(__uint_as_float(q1.y), bf2f(h1), acc);
    }
    for (; i < e; i += 2) {
      uint2 q;
      GETREC2(q, i);
      acc = fmaf(__uint_as_float(q.y),
                 bf2f(H2[(size_t)(q.x & 0xffff) * DD + (q.x >> 16) * NCLS + c]), acc);
    }
  }
#undef GETREC2
  acc += __shfl_xor(acc, 16, 32);  // combine even/odd halves
  float m = acc;
#pragma unroll
  for (int mask = 8; mask >= 1; mask >>= 1) m = fmaxf(m, __shfl_xor(m, mask, 16));
  float ex = expf(acc - m);
#pragma unroll
  for (int mask = 8; mask >= 1; mask >>= 1) ex += __shfl_xor(ex, mask, 16);
  if (v < NN && j == 0) out[(size_t)v * NCLS + c] = acc - m - logf(ex);
}

extern "C" void kernel_launch(void* const* d_in, const int* in_sizes, int n_in,
                              void* d_out, int out_size, void* d_ws, size_t ws_size,
                              hipStream_t stream) {
  const float* x  = (const float*)d_in[0];
  const int*   ei = (const int*)d_in[1];
  const int*   et = (const int*)d_in[2];
  const float* ew = (const float*)d_in[3];
  const float* W1 = (const float*)d_in[4];
  const float* W2 = (const float*)d_in[5];
  float* out = (float*)d_out;
  float* ws = (float*)d_ws;

  // workspace layout (float-unit offsets; ~34 MB)
  int*    cnt    = (int*)ws;                    // 400000
  int*    off    = (int*)(ws + 400000);         // 400001 (+pad)
  int*    bsum   = (int*)(ws + 800004);         // 1563 (+pad)
  int*    bpre   = (int*)(ws + 801568);         // 1563 (+pad)
  int*    cursor = (int*)(ws + 803132);         // 400000
  uint2*  rec    = (uint2*)(ws + 1203132);      // 640000 uint2
  ushort* xb     = (ushort*)(ws + 2483132);     // NN*DD bf16
  ushort* W1Tc   = (ushort*)(ws + 5683132);     // 128*1024 bf16
  ushort* W2T    = (ushort*)(ws + 5748668);     // 128*128 bf16
  ushort* H2     = (ushort*)(ws + 5756860);     // NN*DD bf16

  hipMemsetAsync(cnt, 0, (size_t)NBUCK * sizeof(int), stream);

  countpack_kernel<<<(PACKN + 255) / 256, 256, 0, stream>>>(ei, et, x, W1, W2, cnt, xb, W1Tc, W2T);
  scan1_kernel<<<SCAN_NB, 256, 0, stream>>>(cnt, off, bsum);
  scan2_kernel<<<1, 64, 0, stream>>>(bsum, bpre);
  scan3_kernel<<<SCAN_NB, 256, 0, stream>>>(off, bpre, cursor);
  bucket_kernel<<<(EE + 255) / 256, 256, 0, stream>>>(ei, et, ew, cnt, cursor, rec);

  fused1_kernel<<<(NN + 63) / 64, 512, 0, stream>>>(off, rec, xb, W1Tc, W2T, H2);
  gather2_kernel<<<(NN + 7) / 8, 256, 0, stream>>>(off, rec, H2, out);
}

// Round 4
// 250.072 us; speedup vs baseline: 1.1235x; 1.0282x over previous
//
#include <hip/hip_runtime.h>
#include <hip/hip_bf16.h>
#include <math.h>

#define NN 50000
#define EE 640000
#define DD 128
#define NREL 8
#define NCLS 16
#define NBUCK (NREL * NN)              // 400000 buckets, key = dst*8 + rel
#define RECCAP 40                      // max cached recs/node in LDS
#define OSTR 12                        // offN stride per node (9 used; 12 -> 16B-aligned int4)

typedef __attribute__((ext_vector_type(8))) short short8;   // 8 bf16 = 4 VGPRs
typedef __attribute__((ext_vector_type(4))) float f32x4;    // MFMA acc

__device__ __forceinline__ float bflo(unsigned u) { return __uint_as_float(u << 16); }
__device__ __forceinline__ float bfhi(unsigned u) { return __uint_as_float(u & 0xffff0000u); }
__device__ __forceinline__ float bf2f(ushort u) { return __uint_as_float(((unsigned)u) << 16); }
__device__ __forceinline__ ushort f2b(float f) {  // RNE
  unsigned u = __float_as_uint(f);
  u += 0x7fff + ((u >> 16) & 1);
  return (ushort)(u >> 16);
}

// ---------- merged count (per-(dst,rel) histogram) + pack (x->bf16, W1Tc, W2T) ----------
// W1Tc[n*1024 + r*128 + k] = bf16(W1[r][k][n]); W2T[j*128 + k] = bf16(W2[j>>4][k][j&15])
#define XQ (NN * DD / 4)
#define PACKN (XQ + NREL * DD * DD + DD * DD)
__global__ __launch_bounds__(256) void countpack_kernel(const int* __restrict__ ei,
                                                        const int* __restrict__ et,
                                                        const float* __restrict__ x,
                                                        const float* __restrict__ W1,
                                                        const float* __restrict__ W2,
                                                        int* __restrict__ cnt,
                                                        ushort* __restrict__ xb,
                                                        ushort* __restrict__ W1Tc,
                                                        ushort* __restrict__ W2T) {
  int t = blockIdx.x * 256 + threadIdx.x;
  if (t < EE) {
    int key = ei[EE + t] * NREL + et[t];
    atomicAdd(&cnt[key], 1);
  }
  if (t < XQ) {
    float4 v = *(const float4*)&x[(size_t)t * 4];
    *(ushort4*)&xb[(size_t)t * 4] = make_ushort4(f2b(v.x), f2b(v.y), f2b(v.z), f2b(v.w));
  } else if (t < XQ + NREL * DD * DD) {
    int t2 = t - XQ;
    int n = t2 >> 10, r = (t2 >> 7) & 7, k = t2 & 127;
    W1Tc[t2] = f2b(W1[r * 16384 + k * 128 + n]);
  } else if (t < PACKN) {
    int t2 = t - XQ - NREL * DD * DD;
    int j = t2 >> 7, k = t2 & 127;
    W2T[t2] = f2b(W2[(j >> 4) * (DD * NCLS) + k * NCLS + (j & 15)]);
  }
}

// ---------- per-node segment allocation (replaces the 400K global scan) ----------
// Each node v gets a contiguous rec segment of size deg(v), allocated via one
// wave-aggregated atomicAdd on gcur. offN[v*OSTR + i] (i=0..8) = rel-prefix offsets.
// Node order in rec is arbitrary (only per-node contiguity matters downstream).
__global__ __launch_bounds__(256) void base_kernel(const int* __restrict__ cnt,
                                                   int* __restrict__ gcur,
                                                   int* __restrict__ offN) {
  const int v = blockIdx.x * 256 + threadIdx.x;
  const int lane = threadIdx.x & 63;
  int pre[9];
  pre[0] = 0;
  int deg = 0;
  if (v < NN) {
    int4 c0 = *(const int4*)&cnt[v * 8];
    int4 c1 = *(const int4*)&cnt[v * 8 + 4];
    pre[1] = pre[0] + c0.x;
    pre[2] = pre[1] + c0.y;
    pre[3] = pre[2] + c0.z;
    pre[4] = pre[3] + c0.w;
    pre[5] = pre[4] + c1.x;
    pre[6] = pre[5] + c1.y;
    pre[7] = pre[6] + c1.z;
    pre[8] = pre[7] + c1.w;
    deg = pre[8];
  } else {
#pragma unroll
    for (int i = 1; i < 9; i++) pre[i] = 0;
  }
  // wave-inclusive scan of deg
  int incl = deg;
#pragma unroll
  for (int o = 1; o < 64; o <<= 1) {
    int t = __shfl_up(incl, o, 64);
    if (lane >= o) incl += t;
  }
  int wtotal = __shfl(incl, 63, 64);
  int wbase = 0;
  if (lane == 63) wbase = atomicAdd(gcur, wtotal);
  wbase = __shfl(wbase, 63, 64);
  if (v < NN) {
    int nbase = wbase + incl - deg;
#pragma unroll
    for (int i = 0; i < 9; i++) offN[v * OSTR + i] = nbase + pre[i];
  }
}

// rec word0 = src | rel<<16 ; word1 = ew/cnt (pre-divided mean scale)
// cnt doubles as a countdown cursor (atomicSub); bucket size recomputed from offN.
__global__ __launch_bounds__(256) void bucket_kernel(const int* __restrict__ ei,
                                                     const int* __restrict__ et,
                                                     const float* __restrict__ ew,
                                                     const int* __restrict__ offN,
                                                     int* __restrict__ cnt,
                                                     uint2* __restrict__ rec) {
  int e = blockIdx.x * 256 + threadIdx.x;
  if (e >= EE) return;
  int r = et[e];
  int v = ei[EE + e];
  int b0 = offN[v * OSTR + r];
  int b1 = offN[v * OSTR + r + 1];
  float scale = ew[e] / fmaxf((float)(b1 - b0), 1.0f);
  int pos = b0 + atomicSub(&cnt[v * NREL + r], 1) - 1;
  rec[pos] = make_uint2((unsigned)ei[e] | ((unsigned)r << 16), __float_as_uint(scale));
}

// ---------- fused layer1+layer2: H2 = bf16( relu(gather(x) @ W1cat) @ W2T^T ) ----------
// Proven 82us structure (fabric-bound at the random-64B HBM ceiling): 64 nodes/block,
// 8 thr/node x 16 cols, per-relation walk with 2 edges in flight; rec preloaded to
// LDS; 8 waves each own 16 out-cols; layer-2 GEMM fused on the in-LDS A2 tile.
__global__ __launch_bounds__(512) void fused1_kernel(const int* __restrict__ offN,
                                                     const uint2* __restrict__ rec,
                                                     const ushort* __restrict__ xb,
                                                     const ushort* __restrict__ W1Tc,
                                                     const ushort* __restrict__ W2T,
                                                     ushort* __restrict__ H2) {
  __shared__ ushort AsU[64 * 136];         // 17408 B
  __shared__ uint2 recL[64 * RECCAP];      // 20480 B  (total 37888 B -> 4 blocks/CU)
  const int tid = threadIdx.x;
  const int m0 = blockIdx.x * 64;
  const int wave = tid >> 6, lane = tid & 63;
  const int lm = lane & 15, lkb = (lane >> 4) * 8;
  const int gn = tid >> 3;          // gather: node slot 0..63
  const int gj = tid & 7;           // gather: 8 threads/node
  const int gc = gj * 16;           // gather: col base (16 cols)
  const int v = m0 + gn;

  // hoist the node's 9 offsets (per-node contiguous, rel-ordered)
  int offv[9];
  if (v < NN) {
    int4 o0 = *(const int4*)&offN[v * OSTR];
    int4 o1 = *(const int4*)&offN[v * OSTR + 4];
    offv[0] = o0.x; offv[1] = o0.y; offv[2] = o0.z; offv[3] = o0.w;
    offv[4] = o1.x; offv[5] = o1.y; offv[6] = o1.z; offv[7] = o1.w;
    offv[8] = offN[v * OSTR + 8];
  } else {
#pragma unroll
    for (int i = 0; i < 9; i++) offv[i] = 0;
  }
  const int b0 = offv[0];
  const int rbase = gn * RECCAP;
  {
    int dcap = min(offv[8] - b0, RECCAP);
    for (int i = gj; i < dcap; i += 8) recL[rbase + i] = rec[b0 + i];
  }
  // recL visibility for r=0 is guaranteed by the r-loop's leading __syncthreads

#define GETREC(qdst, ii)                                        \
  do {                                                          \
    int _ri = (ii) - b0;                                        \
    if (_ri < RECCAP) qdst = recL[rbase + _ri];                 \
    else qdst = rec[(ii)];                                      \
  } while (0)

  f32x4 acc[4];
#pragma unroll
  for (int m = 0; m < 4; m++) acc[m] = (f32x4){0.f, 0.f, 0.f, 0.f};

#pragma unroll
  for (int r = 0; r < NREL; r++) {
    __syncthreads();  // previous chunk's AsU reads complete (and r=0: recL ready)
    // register gather, 2 edges in flight, 16 cols (2 uint4) per edge
    float g[16];
#pragma unroll
    for (int j = 0; j < 16; j++) g[j] = 0.f;
    {
      int s = offv[r], e = offv[r + 1];
      int i = s;
      for (; i + 2 <= e; i += 2) {
        uint2 q0, q1;
        GETREC(q0, i);
        GETREC(q1, i + 1);
        float sc0 = __uint_as_float(q0.y), sc1 = __uint_as_float(q1.y);
        const ushort* xr0 = &xb[(size_t)(q0.x & 0xffff) * DD + gc];
        const ushort* xr1 = &xb[(size_t)(q1.x & 0xffff) * DD + gc];
        uint4 h0[2], h1[2];
#pragma unroll
        for (int jj = 0; jj < 2; jj++) h0[jj] = *(const uint4*)&xr0[jj * 8];
#pragma unroll
        for (int jj = 0; jj < 2; jj++) h1[jj] = *(const uint4*)&xr1[jj * 8];
#pragma unroll
        for (int jj = 0; jj < 2; jj++) {
          float* gg = &g[jj * 8];
          gg[0] = fmaf(sc0, bflo(h0[jj].x), gg[0]);
          gg[1] = fmaf(sc0, bfhi(h0[jj].x), gg[1]);
          gg[2] = fmaf(sc0, bflo(h0[jj].y), gg[2]);
          gg[3] = fmaf(sc0, bfhi(h0[jj].y), gg[3]);
          gg[4] = fmaf(sc0, bflo(h0[jj].z), gg[4]);
          gg[5] = fmaf(sc0, bfhi(h0[jj].z), gg[5]);
          gg[6] = fmaf(sc0, bflo(h0[jj].w), gg[6]);
          gg[7] = fmaf(sc0, bfhi(h0[jj].w), gg[7]);
          gg[0] = fmaf(sc1, bflo(h1[jj].x), gg[0]);
          gg[1] = fmaf(sc1, bfhi(h1[jj].x), gg[1]);
          gg[2] = fmaf(sc1, bflo(h1[jj].y), gg[2]);
          gg[3] = fmaf(sc1, bfhi(h1[jj].y), gg[3]);
          gg[4] = fmaf(sc1, bflo(h1[jj].z), gg[4]);
          gg[5] = fmaf(sc1, bfhi(h1[jj].z), gg[5]);
          gg[6] = fmaf(sc1, bflo(h1[jj].w), gg[6]);
          gg[7] = fmaf(sc1, bfhi(h1[jj].w), gg[7]);
        }
      }
      if (i < e) {
        uint2 q;
        GETREC(q, i);
        float sc = __uint_as_float(q.y);
        const ushort* xr = &xb[(size_t)(q.x & 0xffff) * DD + gc];
#pragma unroll
        for (int jj = 0; jj < 2; jj++) {
          uint4 h = *(const uint4*)&xr[jj * 8];
          float* gg = &g[jj * 8];
          gg[0] = fmaf(sc, bflo(h.x), gg[0]);
          gg[1] = fmaf(sc, bfhi(h.x), gg[1]);
          gg[2] = fmaf(sc, bflo(h.y), gg[2]);
          gg[3] = fmaf(sc, bfhi(h.y), gg[3]);
          gg[4] = fmaf(sc, bflo(h.z), gg[4]);
          gg[5] = fmaf(sc, bfhi(h.z), gg[5]);
          gg[6] = fmaf(sc, bflo(h.w), gg[6]);
          gg[7] = fmaf(sc, bfhi(h.w), gg[7]);
        }
      }
    }
#pragma unroll
    for (int jj = 0; jj < 2; jj++) {
      uint4 u;
      u.x = (unsigned)f2b(g[jj * 8 + 0]) | ((unsigned)f2b(g[jj * 8 + 1]) << 16);
      u.y = (unsigned)f2b(g[jj * 8 + 2]) | ((unsigned)f2b(g[jj * 8 + 3]) << 16);
      u.z = (unsigned)f2b(g[jj * 8 + 4]) | ((unsigned)f2b(g[jj * 8 + 5]) << 16);
      u.w = (unsigned)f2b(g[jj * 8 + 6]) | ((unsigned)f2b(g[jj * 8 + 7]) << 16);
      *(uint4*)&AsU[gn * 136 + gc + jj * 8] = u;
    }
    __syncthreads();
    // MFMA: wave owns out-cols [wave*16, wave*16+16); B fragment from L2
#pragma unroll
    for (int k0 = 0; k0 < 128; k0 += 32) {
      short8 b = *(const short8*)&W1Tc[(size_t)(wave * 16 + lm) * 1024 + r * 128 + k0 + lkb];
      short8 a[4];
#pragma unroll
      for (int m = 0; m < 4; m++)
        a[m] = *(const short8*)&AsU[(m * 16 + lm) * 136 + k0 + lkb];
#pragma unroll
      for (int m = 0; m < 4; m++)
        acc[m] = __builtin_amdgcn_mfma_f32_16x16x32_bf16(a[m], b, acc[m], 0, 0, 0);
    }
  }
#undef GETREC

  // ---- epilogue 1: relu -> bf16 A2 tile in LDS ----
  __syncthreads();
  const int rquad = (lane >> 4) * 4;
#pragma unroll
  for (int m = 0; m < 4; m++)
#pragma unroll
    for (int i = 0; i < 4; i++)
      AsU[(m * 16 + rquad + i) * 136 + wave * 16 + lm] = f2b(fmaxf(acc[m][i], 0.f));
  __syncthreads();

  // ---- layer-2 GEMM on the in-LDS A2 tile (W2T from L2) ----
  f32x4 acc2[4];
#pragma unroll
  for (int m = 0; m < 4; m++) acc2[m] = (f32x4){0.f, 0.f, 0.f, 0.f};
#pragma unroll
  for (int k0 = 0; k0 < 128; k0 += 32) {
    short8 b = *(const short8*)&W2T[(size_t)(wave * 16 + lm) * DD + k0 + lkb];
    short8 a[4];
#pragma unroll
    for (int m = 0; m < 4; m++)
      a[m] = *(const short8*)&AsU[(m * 16 + lm) * 136 + k0 + lkb];
#pragma unroll
    for (int m = 0; m < 4; m++)
      acc2[m] = __builtin_amdgcn_mfma_f32_16x16x32_bf16(a[m], b, acc2[m], 0, 0, 0);
  }
  __syncthreads();
#pragma unroll
  for (int m = 0; m < 4; m++)
#pragma unroll
    for (int i = 0; i < 4; i++)
      AsU[(m * 16 + rquad + i) * 136 + wave * 16 + lm] = f2b(acc2[m][i]);
  __syncthreads();
#pragma unroll
  for (int i = 0; i < 2; i++) {
    int seg = tid + i * 512;
    int row = seg >> 4, c8 = (seg & 15) * 8;
    int gr = m0 + row;
    if (gr < NN) *(uint4*)&H2[(size_t)gr * DD + c8] = *(const uint4*)&AsU[row * 136 + c8];
  }
}

// ---------- gather2 + log_softmax ----------
// 8 consecutive nodes/block, 32 lanes/node: even/odd edges processed by the two
// 16-lane halves in parallel (4 edges in flight/node); rec preload to LDS; halves
// combined via shfl_xor(16); fused log-softmax; coalesced out store.
__global__ __launch_bounds__(256) void gather2_kernel(const int* __restrict__ offN,
                                                      const uint2* __restrict__ rec,
                                                      const ushort* __restrict__ H2,
                                                      float* __restrict__ out) {
  __shared__ uint2 recL[8 * RECCAP];  // 2560 B
  const int tid = threadIdx.x;
  const int g = tid >> 5;          // node slot 0..7
  const int sub = tid & 31;
  const int j = sub >> 4;          // edge parity
  const int c = sub & 15;          // class
  const int v = blockIdx.x * 8 + g;
  int s = 0, e = 0;
  if (v < NN) {
    s = offN[v * OSTR];
    e = offN[v * OSTR + 8];
  }
  const int rbase = g * RECCAP;
  {
    int dcap = min(e - s, RECCAP);
    for (int i = sub; i < dcap; i += 32) recL[rbase + i] = rec[s + i];
  }
  __syncthreads();

#define GETREC2(qdst, ii)                                       \
  do {                                                          \
    int _ri = (ii) - s;                                         \
    if (_ri < RECCAP) qdst = recL[rbase + _ri];                 \
    else qdst = rec[(ii)];                                      \
  } while (0)

  float acc = 0.f;
  if (v < NN) {
    int i = s + j;
    for (; i + 2 < e; i += 4) {
      uint2 q0, q1;
      GETREC2(q0, i);
      GETREC2(q1, i + 2);
      ushort h0 = H2[(size_t)(q0.x & 0xffff) * DD + (q0.x >> 16) * NCLS + c];
      ushort h1 = H2[(size_t)(q1.x & 0xffff) * DD + (q1.x >> 16) * NCLS + c];
      acc = fmaf(__uint_as_float(q0.y), bf2f(h0), acc);
      acc = fmaf(__uint_as_float(q1.y), bf2f(h1), acc);
    }
    for (; i < e; i += 2) {
      uint2 q;
      GETREC2(q, i);
      acc = fmaf(__uint_as_float(q.y),
                 bf2f(H2[(size_t)(q.x & 0xffff) * DD + (q.x >> 16) * NCLS + c]), acc);
    }
  }
#undef GETREC2
  acc += __shfl_xor(acc, 16, 32);  // combine even/odd halves
  float m = acc;
#pragma unroll
  for (int mask = 8; mask >= 1; mask >>= 1) m = fmaxf(m, __shfl_xor(m, mask, 16));
  float ex = expf(acc - m);
#pragma unroll
  for (int mask = 8; mask >= 1; mask >>= 1) ex += __shfl_xor(ex, mask, 16);
  if (v < NN && j == 0) out[(size_t)v * NCLS + c] = acc - m - logf(ex);
}

extern "C" void kernel_launch(void* const* d_in, const int* in_sizes, int n_in,
                              void* d_out, int out_size, void* d_ws, size_t ws_size,
                              hipStream_t stream) {
  const float* x  = (const float*)d_in[0];
  const int*   ei = (const int*)d_in[1];
  const int*   et = (const int*)d_in[2];
  const float* ew = (const float*)d_in[3];
  const float* W1 = (const float*)d_in[4];
  const float* W2 = (const float*)d_in[5];
  float* out = (float*)d_out;
  float* ws = (float*)d_ws;

  // workspace layout (float-unit offsets; ~35 MB)
  int*    cnt  = (int*)ws;                    // 400000 (+1 gcur)
  int*    gcur = (int*)(ws + 400000);         // 1
  int*    offN = (int*)(ws + 400004);         // 50000*12 = 600000 (16B-aligned)
  uint2*  rec  = (uint2*)(ws + 1000004);      // 640000 uint2 (16B-aligned)
  ushort* xb   = (ushort*)(ws + 2280004);     // NN*DD bf16 (16B-aligned)
  ushort* W1Tc = (ushort*)(ws + 5480004);     // 128*1024 bf16
  ushort* W2T  = (ushort*)(ws + 5545540);     // 128*128 bf16
  ushort* H2   = (ushort*)(ws + 5553732);     // NN*DD bf16

  hipMemsetAsync(cnt, 0, (size_t)(NBUCK + 1) * sizeof(int), stream);  // cnt + gcur

  countpack_kernel<<<(PACKN + 255) / 256, 256, 0, stream>>>(ei, et, x, W1, W2, cnt, xb, W1Tc, W2T);
  base_kernel<<<(NN + 255) / 256, 256, 0, stream>>>(cnt, gcur, offN);
  bucket_kernel<<<(EE + 255) / 256, 256, 0, stream>>>(ei, et, ew, offN, cnt, rec);

  fused1_kernel<<<(NN + 63) / 64, 512, 0, stream>>>(offN, rec, xb, W1Tc, W2T, H2);
  gather2_kernel<<<(NN + 7) / 8, 256, 0, stream>>>(offN, rec, H2, out);
}

// Round 5
// 248.837 us; speedup vs baseline: 1.1290x; 1.0050x over previous
//
#include <hip/hip_runtime.h>
#include <hip/hip_bf16.h>
#include <math.h>

#define NN 50000
#define EE 640000
#define DD 128
#define NREL 8
#define NCLS 16
#define NBUCK (NREL * NN)              // 400000 buckets, key = dst*8 + rel
#define RECCAP 40                      // max cached recs/node in LDS
#define OSTR 12                        // offN stride per node (9 used; 12 -> 16B-aligned int4)

typedef __attribute__((ext_vector_type(8))) short short8;   // 8 bf16 = 4 VGPRs
typedef __attribute__((ext_vector_type(4))) float f32x4;    // MFMA acc

__device__ __forceinline__ float bflo(unsigned u) { return __uint_as_float(u << 16); }
__device__ __forceinline__ float bfhi(unsigned u) { return __uint_as_float(u & 0xffff0000u); }
__device__ __forceinline__ float bf2f(ushort u) { return __uint_as_float(((unsigned)u) << 16); }
__device__ __forceinline__ ushort f2b(float f) {  // RNE
  unsigned u = __float_as_uint(f);
  u += 0x7fff + ((u >> 16) & 1);
  return (ushort)(u >> 16);
}

// ---------- merged count + pack (x->bf16, W2T) + LDS-tiled W1 transpose ----------
// W1Tc[n*1024 + r*128 + k] = bf16(W1[r][k][n]); W2T[j*128 + k] = bf16(W2[j>>4][k][j&15])
// W1 pack is done by 128 dedicated trailing blocks as a 32x32 LDS transpose:
// coalesced 128B row reads from W1, conflict-free LDS (stride 33), coalesced
// 64B writes to W1Tc. (The old per-thread gather read W1 at stride 512B:
// 16x fetch amplification over the whole 4MB bank.)
#define XQ (NN * DD / 4)
#define PACKB ((XQ + DD * DD) / 256)   // 6314 blocks: xb + W2T (+ count within first 2500)
__global__ __launch_bounds__(256) void countpack_kernel(const int* __restrict__ ei,
                                                        const int* __restrict__ et,
                                                        const float* __restrict__ x,
                                                        const float* __restrict__ W1,
                                                        const float* __restrict__ W2,
                                                        int* __restrict__ cnt,
                                                        ushort* __restrict__ xb,
                                                        ushort* __restrict__ W1Tc,
                                                        ushort* __restrict__ W2T) {
  const int b = blockIdx.x;
  if (b < PACKB) {
    int t = b * 256 + threadIdx.x;
    if (t < EE) {
      int key = ei[EE + t] * NREL + et[t];
      atomicAdd(&cnt[key], 1);
    }
    if (t < XQ) {
      float4 v = *(const float4*)&x[(size_t)t * 4];
      *(ushort4*)&xb[(size_t)t * 4] = make_ushort4(f2b(v.x), f2b(v.y), f2b(v.z), f2b(v.w));
    } else {
      int t2 = t - XQ;  // < DD*DD by grid construction
      int j = t2 >> 7, k = t2 & 127;
      W2T[t2] = f2b(W2[(j >> 4) * (DD * NCLS) + k * NCLS + (j & 15)]);
    }
  } else {
    // W1 transpose: tile bb of 128 (8 rels x 16 tiles of 32x32)
    __shared__ float lt[32][33];
    const int bb = b - PACKB;
    const int r = bb >> 4;
    const int tile = bb & 15;
    const int tk = (tile >> 2) * 32, tn = (tile & 3) * 32;
    const int lj = threadIdx.x & 31, li8 = threadIdx.x >> 5;  // 8 rows per pass
#pragma unroll
    for (int p = 0; p < 4; p++) {
      int i = p * 8 + li8;
      lt[i][lj] = W1[r * 16384 + (tk + i) * 128 + (tn + lj)];  // coalesced 128B
    }
    __syncthreads();
#pragma unroll
    for (int p = 0; p < 4; p++) {
      int i = p * 8 + li8;  // i = n-local, lj = k-local
      W1Tc[(size_t)(tn + i) * 1024 + r * 128 + tk + lj] = f2b(lt[lj][i]);  // coalesced 64B
    }
  }
}

// ---------- per-node segment allocation (replaces the 400K global scan) ----------
// Each node v gets a contiguous rec segment of size deg(v), allocated via one
// wave-aggregated atomicAdd on gcur. offN[v*OSTR + i] (i=0..8) = rel-prefix offsets.
// Node order in rec is arbitrary (only per-node contiguity matters downstream).
__global__ __launch_bounds__(256) void base_kernel(const int* __restrict__ cnt,
                                                   int* __restrict__ gcur,
                                                   int* __restrict__ offN) {
  const int v = blockIdx.x * 256 + threadIdx.x;
  const int lane = threadIdx.x & 63;
  int pre[9];
  pre[0] = 0;
  int deg = 0;
  if (v < NN) {
    int4 c0 = *(const int4*)&cnt[v * 8];
    int4 c1 = *(const int4*)&cnt[v * 8 + 4];
    pre[1] = pre[0] + c0.x;
    pre[2] = pre[1] + c0.y;
    pre[3] = pre[2] + c0.z;
    pre[4] = pre[3] + c0.w;
    pre[5] = pre[4] + c1.x;
    pre[6] = pre[5] + c1.y;
    pre[7] = pre[6] + c1.z;
    pre[8] = pre[7] + c1.w;
    deg = pre[8];
  } else {
#pragma unroll
    for (int i = 1; i < 9; i++) pre[i] = 0;
  }
  // wave-inclusive scan of deg
  int incl = deg;
#pragma unroll
  for (int o = 1; o < 64; o <<= 1) {
    int t = __shfl_up(incl, o, 64);
    if (lane >= o) incl += t;
  }
  int wtotal = __shfl(incl, 63, 64);
  int wbase = 0;
  if (lane == 63) wbase = atomicAdd(gcur, wtotal);
  wbase = __shfl(wbase, 63, 64);
  if (v < NN) {
    int nbase = wbase + incl - deg;
#pragma unroll
    for (int i = 0; i < 9; i++) offN[v * OSTR + i] = nbase + pre[i];
  }
}

// rec word0 = src | rel<<16 ; word1 = ew/cnt (pre-divided mean scale)
// cnt doubles as a countdown cursor (atomicSub); bucket size recomputed from offN.
__global__ __launch_bounds__(256) void bucket_kernel(const int* __restrict__ ei,
                                                     const int* __restrict__ et,
                                                     const float* __restrict__ ew,
                                                     const int* __restrict__ offN,
                                                     int* __restrict__ cnt,
                                                     uint2* __restrict__ rec) {
  int e = blockIdx.x * 256 + threadIdx.x;
  if (e >= EE) return;
  int r = et[e];
  int v = ei[EE + e];
  int b0 = offN[v * OSTR + r];
  int b1 = offN[v * OSTR + r + 1];
  float scale = ew[e] / fmaxf((float)(b1 - b0), 1.0f);
  int pos = b0 + atomicSub(&cnt[v * NREL + r], 1) - 1;
  rec[pos] = make_uint2((unsigned)ei[e] | ((unsigned)r << 16), __float_as_uint(scale));
}

// ---------- fused layer1+layer2: H2 = bf16( relu(gather(x) @ W1cat) @ W2T^T ) ----------
// Proven 81us structure (fabric-bound at the random-64B fetch ceiling): 64 nodes/block,
// 8 thr/node x 16 cols, per-relation walk with 2 edges in flight; rec preloaded to
// LDS; 8 waves each own 16 out-cols; layer-2 GEMM fused on the in-LDS A2 tile.
__global__ __launch_bounds__(512) void fused1_kernel(const int* __restrict__ offN,
                                                     const uint2* __restrict__ rec,
                                                     const ushort* __restrict__ xb,
                                                     const ushort* __restrict__ W1Tc,
                                                     const ushort* __restrict__ W2T,
                                                     ushort* __restrict__ H2) {
  __shared__ ushort AsU[64 * 136];         // 17408 B
  __shared__ uint2 recL[64 * RECCAP];      // 20480 B  (total 37888 B -> 4 blocks/CU)
  const int tid = threadIdx.x;
  const int m0 = blockIdx.x * 64;
  const int wave = tid >> 6, lane = tid & 63;
  const int lm = lane & 15, lkb = (lane >> 4) * 8;
  const int gn = tid >> 3;          // gather: node slot 0..63
  const int gj = tid & 7;           // gather: 8 threads/node
  const int gc = gj * 16;           // gather: col base (16 cols)
  const int v = m0 + gn;

  // hoist the node's 9 offsets (per-node contiguous, rel-ordered)
  int offv[9];
  if (v < NN) {
    int4 o0 = *(const int4*)&offN[v * OSTR];
    int4 o1 = *(const int4*)&offN[v * OSTR + 4];
    offv[0] = o0.x; offv[1] = o0.y; offv[2] = o0.z; offv[3] = o0.w;
    offv[4] = o1.x; offv[5] = o1.y; offv[6] = o1.z; offv[7] = o1.w;
    offv[8] = offN[v * OSTR + 8];
  } else {
#pragma unroll
    for (int i = 0; i < 9; i++) offv[i] = 0;
  }
  const int b0 = offv[0];
  const int rbase = gn * RECCAP;
  {
    int dcap = min(offv[8] - b0, RECCAP);
    for (int i = gj; i < dcap; i += 8) recL[rbase + i] = rec[b0 + i];
  }
  // recL visibility for r=0 is guaranteed by the r-loop's leading __syncthreads

#define GETREC(qdst, ii)                                        \
  do {                                                          \
    int _ri = (ii) - b0;                                        \
    if (_ri < RECCAP) qdst = recL[rbase + _ri];                 \
    else qdst = rec[(ii)];                                      \
  } while (0)

  f32x4 acc[4];
#pragma unroll
  for (int m = 0; m < 4; m++) acc[m] = (f32x4){0.f, 0.f, 0.f, 0.f};

#pragma unroll
  for (int r = 0; r < NREL; r++) {
    __syncthreads();  // previous chunk's AsU reads complete (and r=0: recL ready)
    // register gather, 2 edges in flight, 16 cols (2 uint4) per edge
    float g[16];
#pragma unroll
    for (int j = 0; j < 16; j++) g[j] = 0.f;
    {
      int s = offv[r], e = offv[r + 1];
      int i = s;
      for (; i + 2 <= e; i += 2) {
        uint2 q0, q1;
        GETREC(q0, i);
        GETREC(q1, i + 1);
        float sc0 = __uint_as_float(q0.y), sc1 = __uint_as_float(q1.y);
        const ushort* xr0 = &xb[(size_t)(q0.x & 0xffff) * DD + gc];
        const ushort* xr1 = &xb[(size_t)(q1.x & 0xffff) * DD + gc];
        uint4 h0[2], h1[2];
#pragma unroll
        for (int jj = 0; jj < 2; jj++) h0[jj] = *(const uint4*)&xr0[jj * 8];
#pragma unroll
        for (int jj = 0; jj < 2; jj++) h1[jj] = *(const uint4*)&xr1[jj * 8];
#pragma unroll
        for (int jj = 0; jj < 2; jj++) {
          float* gg = &g[jj * 8];
          gg[0] = fmaf(sc0, bflo(h0[jj].x), gg[0]);
          gg[1] = fmaf(sc0, bfhi(h0[jj].x), gg[1]);
          gg[2] = fmaf(sc0, bflo(h0[jj].y), gg[2]);
          gg[3] = fmaf(sc0, bfhi(h0[jj].y), gg[3]);
          gg[4] = fmaf(sc0, bflo(h0[jj].z), gg[4]);
          gg[5] = fmaf(sc0, bfhi(h0[jj].z), gg[5]);
          gg[6] = fmaf(sc0, bflo(h0[jj].w), gg[6]);
          gg[7] = fmaf(sc0, bfhi(h0[jj].w), gg[7]);
          gg[0] = fmaf(sc1, bflo(h1[jj].x), gg[0]);
          gg[1] = fmaf(sc1, bfhi(h1[jj].x), gg[1]);
          gg[2] = fmaf(sc1, bflo(h1[jj].y), gg[2]);
          gg[3] = fmaf(sc1, bfhi(h1[jj].y), gg[3]);
          gg[4] = fmaf(sc1, bflo(h1[jj].z), gg[4]);
          gg[5] = fmaf(sc1, bfhi(h1[jj].z), gg[5]);
          gg[6] = fmaf(sc1, bflo(h1[jj].w), gg[6]);
          gg[7] = fmaf(sc1, bfhi(h1[jj].w), gg[7]);
        }
      }
      if (i < e) {
        uint2 q;
        GETREC(q, i);
        float sc = __uint_as_float(q.y);
        const ushort* xr = &xb[(size_t)(q.x & 0xffff) * DD + gc];
#pragma unroll
        for (int jj = 0; jj < 2; jj++) {
          uint4 h = *(const uint4*)&xr[jj * 8];
          float* gg = &g[jj * 8];
          gg[0] = fmaf(sc, bflo(h.x), gg[0]);
          gg[1] = fmaf(sc, bfhi(h.x), gg[1]);
          gg[2] = fmaf(sc, bflo(h.y), gg[2]);
          gg[3] = fmaf(sc, bfhi(h.y), gg[3]);
          gg[4] = fmaf(sc, bflo(h.z), gg[4]);
          gg[5] = fmaf(sc, bfhi(h.z), gg[5]);
          gg[6] = fmaf(sc, bflo(h.w), gg[6]);
          gg[7] = fmaf(sc, bfhi(h.w), gg[7]);
        }
      }
    }
#pragma unroll
    for (int jj = 0; jj < 2; jj++) {
      uint4 u;
      u.x = (unsigned)f2b(g[jj * 8 + 0]) | ((unsigned)f2b(g[jj * 8 + 1]) << 16);
      u.y = (unsigned)f2b(g[jj * 8 + 2]) | ((unsigned)f2b(g[jj * 8 + 3]) << 16);
      u.z = (unsigned)f2b(g[jj * 8 + 4]) | ((unsigned)f2b(g[jj * 8 + 5]) << 16);
      u.w = (unsigned)f2b(g[jj * 8 + 6]) | ((unsigned)f2b(g[jj * 8 + 7]) << 16);
      *(uint4*)&AsU[gn * 136 + gc + jj * 8] = u;
    }
    __syncthreads();
    // MFMA: wave owns out-cols [wave*16, wave*16+16); B fragment from L2
#pragma unroll
    for (int k0 = 0; k0 < 128; k0 += 32) {
      short8 b = *(const short8*)&W1Tc[(size_t)(wave * 16 + lm) * 1024 + r * 128 + k0 + lkb];
      short8 a[4];
#pragma unroll
      for (int m = 0; m < 4; m++)
        a[m] = *(const short8*)&AsU[(m * 16 + lm) * 136 + k0 + lkb];
#pragma unroll
      for (int m = 0; m < 4; m++)
        acc[m] = __builtin_amdgcn_mfma_f32_16x16x32_bf16(a[m], b, acc[m], 0, 0, 0);
    }
  }
#undef GETREC

  // ---- epilogue 1: relu -> bf16 A2 tile in LDS ----
  __syncthreads();
  const int rquad = (lane >> 4) * 4;
#pragma unroll
  for (int m = 0; m < 4; m++)
#pragma unroll
    for (int i = 0; i < 4; i++)
      AsU[(m * 16 + rquad + i) * 136 + wave * 16 + lm] = f2b(fmaxf(acc[m][i], 0.f));
  __syncthreads();

  // ---- layer-2 GEMM on the in-LDS A2 tile (W2T from L2) ----
  f32x4 acc2[4];
#pragma unroll
  for (int m = 0; m < 4; m++) acc2[m] = (f32x4){0.f, 0.f, 0.f, 0.f};
#pragma unroll
  for (int k0 = 0; k0 < 128; k0 += 32) {
    short8 b = *(const short8*)&W2T[(size_t)(wave * 16 + lm) * DD + k0 + lkb];
    short8 a[4];
#pragma unroll
    for (int m = 0; m < 4; m++)
      a[m] = *(const short8*)&AsU[(m * 16 + lm) * 136 + k0 + lkb];
#pragma unroll
    for (int m = 0; m < 4; m++)
      acc2[m] = __builtin_amdgcn_mfma_f32_16x16x32_bf16(a[m], b, acc2[m], 0, 0, 0);
  }
  __syncthreads();
#pragma unroll
  for (int m = 0; m < 4; m++)
#pragma unroll
    for (int i = 0; i < 4; i++)
      AsU[(m * 16 + rquad + i) * 136 + wave * 16 + lm] = f2b(acc2[m][i]);
  __syncthreads();
#pragma unroll
  for (int i = 0; i < 2; i++) {
    int seg = tid + i * 512;
    int row = seg >> 4, c8 = (seg & 15) * 8;
    int gr = m0 + row;
    if (gr < NN) *(uint4*)&H2[(size_t)gr * DD + c8] = *(const uint4*)&AsU[row * 136 + c8];
  }
}

// ---------- gather2 + log_softmax ----------
// 8 consecutive nodes/block, 32 lanes/node: even/odd edges processed by the two
// 16-lane halves in parallel (4 edges in flight/node); rec preload to LDS; halves
// combined via shfl_xor(16); fused log-softmax; coalesced out store.
__global__ __launch_bounds__(256) void gather2_kernel(const int* __restrict__ offN,
                                                      const uint2* __restrict__ rec,
                                                      const ushort* __restrict__ H2,
                                                      float* __restrict__ out) {
  __shared__ uint2 recL[8 * RECCAP];  // 2560 B
  const int tid = threadIdx.x;
  const int g = tid >> 5;          // node slot 0..7
  const int sub = tid & 31;
  const int j = sub >> 4;          // edge parity
  const int c = sub & 15;          // class
  const int v = blockIdx.x * 8 + g;
  int s = 0, e = 0;
  if (v < NN) {
    s = offN[v * OSTR];
    e = offN[v * OSTR + 8];
  }
  const int rbase = g * RECCAP;
  {
    int dcap = min(e - s, RECCAP);
    for (int i = sub; i < dcap; i += 32) recL[rbase + i] = rec[s + i];
  }
  __syncthreads();

#define GETREC2(qdst, ii)                                       \
  do {                                                          \
    int _ri = (ii) - s;                                         \
    if (_ri < RECCAP) qdst = recL[rbase + _ri];                 \
    else qdst = rec[(ii)];                                      \
  } while (0)

  float acc = 0.f;
  if (v < NN) {
    int i = s + j;
    for (; i + 2 < e; i += 4) {
      uint2 q0, q1;
      GETREC2(q0, i);
      GETREC2(q1, i + 2);
      ushort h0 = H2[(size_t)(q0.x & 0xffff) * DD + (q0.x >> 16) * NCLS + c];
      ushort h1 = H2[(size_t)(q1.x & 0xffff) * DD + (q1.x >> 16) * NCLS + c];
      acc = fmaf(__uint_as_float(q0.y), bf2f(h0), acc);
      acc = fmaf(__uint_as_float(q1.y), bf2f(h1), acc);
    }
    for (; i < e; i += 2) {
      uint2 q;
      GETREC2(q, i);
      acc = fmaf(__uint_as_float(q.y),
                 bf2f(H2[(size_t)(q.x & 0xffff) * DD + (q.x >> 16) * NCLS + c]), acc);
    }
  }
#undef GETREC2
  acc += __shfl_xor(acc, 16, 32);  // combine even/odd halves
  float m = acc;
#pragma unroll
  for (int mask = 8; mask >= 1; mask >>= 1) m = fmaxf(m, __shfl_xor(m, mask, 16));
  float ex = expf(acc - m);
#pragma unroll
  for (int mask = 8; mask >= 1; mask >>= 1) ex += __shfl_xor(ex, mask, 16);
  if (v < NN && j == 0) out[(size_t)v * NCLS + c] = acc - m - logf(ex);
}

extern "C" void kernel_launch(void* const* d_in, const int* in_sizes, int n_in,
                              void* d_out, int out_size, void* d_ws, size_t ws_size,
                              hipStream_t stream) {
  const float* x  = (const float*)d_in[0];
  const int*   ei = (const int*)d_in[1];
  const int*   et = (const int*)d_in[2];
  const float* ew = (const float*)d_in[3];
  const float* W1 = (const float*)d_in[4];
  const float* W2 = (const float*)d_in[5];
  float* out = (float*)d_out;
  float* ws = (float*)d_ws;

  // workspace layout (float-unit offsets; ~35 MB)
  int*    cnt  = (int*)ws;                    // 400000 (+1 gcur)
  int*    gcur = (int*)(ws + 400000);         // 1
  int*    offN = (int*)(ws + 400004);         // 50000*12 = 600000 (16B-aligned)
  uint2*  rec  = (uint2*)(ws + 1000004);      // 640000 uint2 (16B-aligned)
  ushort* xb   = (ushort*)(ws + 2280004);     // NN*DD bf16 (16B-aligned)
  ushort* W1Tc = (ushort*)(ws + 5480004);     // 128*1024 bf16
  ushort* W2T  = (ushort*)(ws + 5545540);     // 128*128 bf16
  ushort* H2   = (ushort*)(ws + 5553732);     // NN*DD bf16

  hipMemsetAsync(cnt, 0, (size_t)(NBUCK + 1) * sizeof(int), stream);  // cnt + gcur

  countpack_kernel<<<PACKB + 128, 256, 0, stream>>>(ei, et, x, W1, W2, cnt, xb, W1Tc, W2T);
  base_kernel<<<(NN + 255) / 256, 256, 0, stream>>>(cnt, gcur, offN);
  bucket_kernel<<<(EE + 255) / 256, 256, 0, stream>>>(ei, et, ew, offN, cnt, rec);

  fused1_kernel<<<(NN + 63) / 64, 512, 0, stream>>>(offN, rec, xb, W1Tc, W2T, H2);
  gather2_kernel<<<(NN + 7) / 8, 256, 0, stream>>>(offN, rec, H2, out);
}